// Round 19
// baseline (77.394 us; speedup 1.0000x reference)
//
#include <hip/hip_runtime.h>

typedef __attribute__((ext_vector_type(8))) short short8;
typedef __attribute__((ext_vector_type(4))) float f32x4;

#define D_KV   64
#define SEQ    4096
#define NBATCH 4
#define DMODEL 1024

static __device__ __forceinline__ unsigned short f32_to_bf16(float f) {
  unsigned u = __builtin_bit_cast(unsigned, f);
  u = (u + 0x7FFFu + ((u >> 16) & 1u)) >> 16;  // round-nearest-even
  return (unsigned short)u;
}

// async global->LDS DMA, 16B/lane; dst wave-uniform (HW adds lane*16)
static __device__ __forceinline__ void gload_lds16(const void* gsrc, void* ldst) {
  __builtin_amdgcn_global_load_lds(
      (const __attribute__((address_space(1))) void*)gsrc,
      (__attribute__((address_space(3))) void*)ldst, 16, 0, 0);
}

// ---------------- kernel 0: x f32 -> bf16 in MFMA-A-fragment order ----------
// (R13-verified; measured 10.6us ~ streaming floor)
__global__ __launch_bounds__(256) void xfrag_kernel(
    const float* __restrict__ x, unsigned short* __restrict__ xfrag) {
  __shared__ unsigned short lt[16 * 1024];  // 32KB, plain [row][col]
  const int tid = threadIdx.x;
  const long T = blockIdx.x;  // 16-row tile, 0..1023
  {
    const int row = tid >> 4, seg = tid & 15;
    const float* src = x + (T * 16 + row) * DMODEL + seg * 64;
    unsigned short* dst = lt + row * 1024 + seg * 64;
#pragma unroll
    for (int j = 0; j < 8; ++j) {
      const f32x4 f0 = *reinterpret_cast<const f32x4*>(src + j * 8);
      const f32x4 f1 = *reinterpret_cast<const f32x4*>(src + j * 8 + 4);
      short8 s;
#pragma unroll
      for (int q = 0; q < 4; ++q) {
        s[q] = (short)f32_to_bf16(f0[q]);
        s[4 + q] = (short)f32_to_bf16(f1[q]);
      }
      *reinterpret_cast<short8*>(dst + j * 8) = s;
    }
  }
  __syncthreads();
  unsigned short* dst = xfrag + T * 16384;
#pragma unroll
  for (int i = 0; i < 8; ++i) {
    const int slot = i * 256 + tid;  // slot = ks*64 + lane
    const int lane2 = slot & 63, ks = slot >> 6;
    const short8 v = *reinterpret_cast<const short8*>(
        lt + (lane2 & 15) * 1024 + ks * 32 + (lane2 >> 4) * 8);
    *reinterpret_cast<short8*>(dst + slot * 8) = v;
  }
}

// ---------------- kernel 1: weights f32 -> bf16, MFMA-fragment order --------
__global__ __launch_bounds__(256) void wcvt_kernel(
    const float* __restrict__ wq, const float* __restrict__ wk,
    const float* __restrict__ wv, unsigned short* __restrict__ wfrag) {
  const int fid = blockIdx.x * 256 + threadIdx.x;  // 0..24575
  const int nt = fid >> 11, ks = (fid >> 6) & 31, lane = fid & 63;
  const int l16 = lane & 15, lq = lane >> 4;
  const float* w = (nt < 4) ? wq : (nt < 8) ? wk : wv;
  const float* src = w + ((nt & 3) * 16 + l16) * DMODEL + ks * 32 + lq * 8;
  short8 v;
#pragma unroll
  for (int j = 0; j < 8; ++j) v[j] = (short)f32_to_bf16(src[j]);
  *reinterpret_cast<short8*>(wfrag + (long)fid * 8) = v;
}

// ---------------- kernel 2: QKV matmul — weights in LDS (96KB, corrected) ---
// 256 blocks = 64 row-groups(256 rows) x 4 nt-quarters(3 nt), 512 threads.
// Block stages its quarter's FULL 96KB weights (96 slots of 1KB; 12/wave)
// via linear DMA + 1 barrier, then a barrier-free K-loop with ZERO weight
// global loads: 8 xfrag loads + 12 ds_read_b128 + 24 MFMAs per chunk/wave.
__global__ __launch_bounds__(512) void qkv_proj_kernel(
    const unsigned short* __restrict__ xfrag,
    const unsigned short* __restrict__ wfrag,
    const float* __restrict__ bq, const float* __restrict__ bk,
    const float* __restrict__ bv,
    unsigned short* __restrict__ Qf, unsigned short* __restrict__ Kf,
    unsigned short* __restrict__ Vf) {
  __shared__ __align__(16) unsigned short lds_w[49152];  // 96KB: 3nt x 32ks x 1KB
  const int tid = threadIdx.x, lane = tid & 63, wave = tid >> 6;  // wave 0..7
  const int l16 = lane & 15, lq = lane >> 4;
  const int quarter = blockIdx.x & 3;        // nt = 3*quarter + i
  const long group = blockIdx.x >> 2;        // 256-row group, 0..63

  // ---- stage weights: 96 x 1KB slots, 12 per wave, linear DMA -------------
  const unsigned char* wsrc =
      (const unsigned char*)(wfrag + (long)(3 * quarter) * 16384);
  unsigned char* wl = (unsigned char*)lds_w;
#pragma unroll
  for (int s = 0; s < 12; ++s) {
    const int slot = wave * 12 + s;  // slot = ntl*32 + ks
    gload_lds16(wsrc + slot * 1024 + lane * 16, wl + slot * 1024);
  }
  __syncthreads();  // drains DMA (compiler emits vmcnt(0) before barrier)

  // ---- K-loop: wave owns tiles 2*wave, 2*wave+1 of this 256-row group -----
  const long T0 = group * 16 + 2 * wave;
  const unsigned short* a0 = xfrag + T0 * 16384 + lane * 8;
  const unsigned short* a1 = a0 + 16384;
  const unsigned char* wlane = wl + lane * 16;

  f32x4 acc[3][2];
#pragma unroll
  for (int i = 0; i < 3; ++i)
#pragma unroll
    for (int p = 0; p < 2; ++p) acc[i][p] = (f32x4){0.f, 0.f, 0.f, 0.f};

#pragma unroll
  for (int ck = 0; ck < 8; ++ck) {
    short8 a[4][2], bw[12];
#pragma unroll
    for (int kc = 0; kc < 4; ++kc) {
      a[kc][0] = *reinterpret_cast<const short8*>(a0 + (ck * 4 + kc) * 512);
      a[kc][1] = *reinterpret_cast<const short8*>(a1 + (ck * 4 + kc) * 512);
    }
#pragma unroll
    for (int i = 0; i < 3; ++i)
#pragma unroll
      for (int kc = 0; kc < 4; ++kc)
        bw[i * 4 + kc] = *reinterpret_cast<const short8*>(
            wlane + (i * 32 + ck * 4 + kc) * 1024);
#pragma unroll
    for (int kc = 0; kc < 4; ++kc)
#pragma unroll
      for (int i = 0; i < 3; ++i) {
        acc[i][0] = __builtin_amdgcn_mfma_f32_16x16x32_bf16(
            a[kc][0], bw[i * 4 + kc], acc[i][0], 0, 0, 0);
        acc[i][1] = __builtin_amdgcn_mfma_f32_16x16x32_bf16(
            a[kc][1], bw[i * 4 + kc], acc[i][1], 0, 0, 0);
      }
  }

  // ---- epilogue: fragment-order stores (R13/R17-verified formulas) --------
#pragma unroll
  for (int i = 0; i < 3; ++i) {
    const int nt = 3 * quarter + i;
    const int mat = nt >> 2;
    const int dcol = ((nt & 3) << 4) | l16;
    const float bias = (mat == 0 ? bq : mat == 1 ? bk : bv)[dcol];
    const int c = dcol >> 5, lqp = (dcol >> 3) & 3, jj = dcol & 7;
#pragma unroll
    for (int p = 0; p < 2; ++p)
#pragma unroll
      for (int rr = 0; rr < 4; ++rr) {
        const long t = (T0 + p) * 16 + lq * 4 + rr;
        const float sum = acc[i][p][rr] + bias;
        if (mat == 0) {
          Qf[(((t >> 4) * 2 + c) * 64 + lqp * 16 + (t & 15)) * 8 + jj] =
              f32_to_bf16(sum * 0.125f);  // fold 1/sqrt(64)
        } else if (mat == 1) {
          Kf[((((t >> 6) * 4 + ((t >> 4) & 3)) * 2 + c) * 64 + lqp * 16 +
              (t & 15)) * 8 + jj] = f32_to_bf16(sum);
        } else {
          Vf[((((t >> 6) * 4 + (dcol >> 4)) * 2 + ((t >> 5) & 1)) * 64 +
              ((t >> 3) & 3) * 16 + (dcol & 15)) * 8 + (t & 7)] =
              f32_to_bf16(sum);
        }
      }
  }
}

// ---------------- kernel 3: causal flash attention, 8-wave split-K ----------
// R16 verbatim (best measured).
__global__ __launch_bounds__(512) void attn_kernel(
    const unsigned short* __restrict__ Qf, const unsigned short* __restrict__ Kf,
    const unsigned short* __restrict__ Vf, float* __restrict__ out) {
  __shared__ __align__(16) unsigned short p_lds[8][16][72];
  __shared__ __align__(16) float lds_o[8][16][68];
  __shared__ float lds_ml[8][16][2];
  __shared__ float lds_gl[16];

  const int tid = threadIdx.x;
  const int lane = tid & 63;
  const int wave = tid >> 6;  // 0..7
  const int l16 = lane & 15, lq = lane >> 4;
  const int b = blockIdx.y;
  const int tile = 255 - blockIdx.x;
  const int qbase = tile * 16;
  const long qrow = (long)b * SEQ + qbase;

  short8 qf[2];
#pragma unroll
  for (int c = 0; c < 2; ++c)
    qf[c] = *reinterpret_cast<const short8*>(
        Qf + ((qrow >> 4) * 2 + c) * 512 + lane * 8);

  f32x4 o[4];
#pragma unroll
  for (int dt = 0; dt < 4; ++dt) o[dt] = (f32x4){0.f, 0.f, 0.f, 0.f};
  float m = -INFINITY, ell = 0.f;

  const long ktile0 = (long)b * 64;
  const int nkv = qbase / 64 + 1;
  for (int kt = wave; kt < nkv; kt += 8) {
    const int kvbase = kt * 64;
    const unsigned short* kb = Kf + (ktile0 + kt) * 4096 + lane * 8;
    const unsigned short* vb = Vf + (ktile0 + kt) * 4096 + lane * 8;
    f32x4 s[4];
#pragma unroll
    for (int ct = 0; ct < 4; ++ct) s[ct] = (f32x4){0.f, 0.f, 0.f, 0.f};
#pragma unroll
    for (int ct = 0; ct < 4; ++ct)
#pragma unroll
      for (int c = 0; c < 2; ++c) {
        short8 kf = *reinterpret_cast<const short8*>(kb + (ct * 2 + c) * 512);
        s[ct] = __builtin_amdgcn_mfma_f32_16x16x32_bf16(kf, qf[c], s[ct], 0, 0, 0);
      }
    if (kt == nkv - 1) {
      const int qg = qbase + l16;
#pragma unroll
      for (int ct = 0; ct < 4; ++ct)
#pragma unroll
        for (int r = 0; r < 4; ++r)
          if (kvbase + ct * 16 + lq * 4 + r > qg) s[ct][r] = -INFINITY;
    }
    float mx = -INFINITY;
#pragma unroll
    for (int ct = 0; ct < 4; ++ct)
#pragma unroll
      for (int r = 0; r < 4; ++r) mx = fmaxf(mx, s[ct][r]);
    mx = fmaxf(mx, __shfl_xor(mx, 16, 64));
    mx = fmaxf(mx, __shfl_xor(mx, 32, 64));
    const float nm = fmaxf(m, mx);
    const float alpha = __expf(m - nm);
    float rs = 0.f;
#pragma unroll
    for (int ct = 0; ct < 4; ++ct)
#pragma unroll
      for (int r = 0; r < 4; ++r) {
        const float p = __expf(s[ct][r] - nm);
        s[ct][r] = p;
        rs += p;
      }
    rs += __shfl_xor(rs, 16, 64);
    rs += __shfl_xor(rs, 32, 64);
    ell = ell * alpha + rs;
    m = nm;
#pragma unroll
    for (int dt = 0; dt < 4; ++dt) o[dt] *= alpha;
#pragma unroll
    for (int ct = 0; ct < 4; ++ct)
#pragma unroll
      for (int r = 0; r < 4; ++r)
        p_lds[wave][l16][ct * 16 + lq * 4 + r] = f32_to_bf16(s[ct][r]);
    short8 pf[2];
#pragma unroll
    for (int c = 0; c < 2; ++c)
      pf[c] = *reinterpret_cast<const short8*>(&p_lds[wave][l16][c * 32 + lq * 8]);
#pragma unroll
    for (int dt = 0; dt < 4; ++dt)
#pragma unroll
      for (int c = 0; c < 2; ++c) {
        short8 vf = *reinterpret_cast<const short8*>(vb + (dt * 2 + c) * 512);
        o[dt] = __builtin_amdgcn_mfma_f32_16x16x32_bf16(vf, pf[c], o[dt], 0, 0, 0);
      }
  }

  if (lane < 16) {
    lds_ml[wave][l16][0] = m;
    lds_ml[wave][l16][1] = ell;
  }
  __syncthreads();
  float g = -INFINITY;
#pragma unroll
  for (int w2 = 0; w2 < 8; ++w2) g = fmaxf(g, lds_ml[w2][l16][0]);
  float gl = 0.f;
#pragma unroll
  for (int w2 = 0; w2 < 8; ++w2)
    gl += lds_ml[w2][l16][1] * __expf(lds_ml[w2][l16][0] - g);
  const float myscale = __expf(m - g);
  if (wave == 0 && lane < 16) lds_gl[l16] = gl;
#pragma unroll
  for (int dt = 0; dt < 4; ++dt)
#pragma unroll
    for (int r = 0; r < 4; ++r)
      lds_o[wave][l16][dt * 16 + lq * 4 + r] = o[dt][r] * myscale;
  __syncthreads();
#pragma unroll
  for (int j = 0; j < 2; ++j) {
    const int e = tid + 512 * j;
    const int row = e >> 6, col = e & 63;
    float sum = 0.f;
#pragma unroll
    for (int w2 = 0; w2 < 8; ++w2) sum += lds_o[w2][row][col];
    out[(qrow + row) * D_KV + col] = sum / lds_gl[row];
  }
}

// ---------------- launch ----------------------------------------------------
extern "C" void kernel_launch(void* const* d_in, const int* in_sizes, int n_in,
                              void* d_out, int out_size, void* d_ws, size_t ws_size,
                              hipStream_t stream) {
  const float* x  = (const float*)d_in[0];
  const float* wq = (const float*)d_in[1];
  const float* bq = (const float*)d_in[2];
  const float* wk = (const float*)d_in[3];
  const float* bk = (const float*)d_in[4];
  const float* wv = (const float*)d_in[5];
  const float* bv = (const float*)d_in[6];
  float* out = (float*)d_out;

  unsigned short* ws    = (unsigned short*)d_ws;
  unsigned short* wfrag = ws;               // 196608 shorts (384KB)
  unsigned short* Qf    = ws + 196608;      // 1048576 shorts
  unsigned short* Kf    = Qf + 1048576;
  unsigned short* Vf    = Kf + 1048576;
  unsigned short* xfrag = Vf + 1048576;     // 16777216 shorts (32MB)

  xfrag_kernel<<<1024, 256, 0, stream>>>(x, xfrag);
  wcvt_kernel<<<96, 256, 0, stream>>>(wq, wk, wv, wfrag);
  qkv_proj_kernel<<<256, 512, 0, stream>>>(xfrag, wfrag, bq, bk, bv, Qf, Kf, Vf);
  dim3 ag(256, NBATCH);
  attn_kernel<<<ag, 512, 0, stream>>>(Qf, Kf, Vf, out);
}

// Round 20
// 61.133 us; speedup vs baseline: 1.2660x; 1.2660x over previous
//
#include <hip/hip_runtime.h>

typedef __attribute__((ext_vector_type(8))) short short8;
typedef __attribute__((ext_vector_type(4))) float f32x4;

#define D_KV   64
#define SEQ    4096
#define NBATCH 4
#define DMODEL 1024

static __device__ __forceinline__ unsigned short f32_to_bf16(float f) {
  unsigned u = __builtin_bit_cast(unsigned, f);
  u = (u + 0x7FFFu + ((u >> 16) & 1u)) >> 16;  // round-nearest-even
  return (unsigned short)u;
}

// ---------------- kernel 1: weights f32 -> bf16, MFMA-fragment order --------
// wfrag[((nt*32 + ks)*64 + lane)*8 + j] = W_mat[(nt&3)*16 + (lane&15)]
//                                             [ks*32 + (lane>>4)*8 + j]
__global__ __launch_bounds__(256) void wcvt_kernel(
    const float* __restrict__ wq, const float* __restrict__ wk,
    const float* __restrict__ wv, unsigned short* __restrict__ wfrag) {
  const int fid = blockIdx.x * 256 + threadIdx.x;  // 0..24575
  const int nt = fid >> 11, ks = (fid >> 6) & 31, lane = fid & 63;
  const int l16 = lane & 15, lq = lane >> 4;
  const float* w = (nt < 4) ? wq : (nt < 8) ? wk : wv;
  const float* src = w + ((nt & 3) * 16 + l16) * DMODEL + ks * 32 + lq * 8;
  short8 v;
#pragma unroll
  for (int j = 0; j < 8; ++j) v[j] = (short)f32_to_bf16(src[j]);
  *reinterpret_cast<short8*>(wfrag + (long)fid * 8) = v;
}

// ---------------- kernel 2: QKV projection (R8 verbatim — best measured) ----
// 512 blocks x 32 rows x 8 waves: 2 blocks/CU x 8 waves = 4 waves/SIMD.
// Wave w: nt-trio 3*(w&3) for row-subtile (w>>2). x staged per 128-K-chunk
// into double-buffered XOR-swizzled LDS (2 x 8KB).
__global__ __launch_bounds__(512) void qkv_proj_kernel(
    const float* __restrict__ x, const unsigned short* __restrict__ wfrag,
    const float* __restrict__ bq, const float* __restrict__ bk,
    const float* __restrict__ bv,
    unsigned short* __restrict__ Qf, unsigned short* __restrict__ Kf,
    unsigned short* __restrict__ Vf) {
  __shared__ __align__(16) unsigned short lds_x[2 * 32 * 128];  // 2 x 8KB
  const int tid = threadIdx.x, lane = tid & 63, wave = tid >> 6;
  const int l16 = lane & 15, lq = lane >> 4;
  const int sub = wave >> 2;          // 0 or 1: 16-row subtile
  const int trio = wave & 3;          // nt = 3*trio + i
  const long rowbase = (long)blockIdx.x * 32;

  const int r = tid >> 4, oct = tid & 15;
  const float* xrow = x + (rowbase + r) * DMODEL + oct * 8;
  unsigned char* lx = (unsigned char*)lds_x;  // buf b at byte offset b*8192
  const int wr_off = r * 256 + ((oct * 16) ^ ((r & 7) << 4));

  f32x4 acc[3];
#pragma unroll
  for (int i = 0; i < 3; ++i) acc[i] = (f32x4){0.f, 0.f, 0.f, 0.f};

  const unsigned short* wbase = wfrag + (long)(3 * trio) * 16384 + lane * 8;
  const int arow = sub * 16 + l16;

  f32x4 x0, x1;
  x0 = *reinterpret_cast<const f32x4*>(xrow);
  x1 = *reinterpret_cast<const f32x4*>(xrow + 4);
  {
    short8 xs;
#pragma unroll
    for (int j = 0; j < 4; ++j) {
      xs[j] = (short)f32_to_bf16(x0[j]);
      xs[4 + j] = (short)f32_to_bf16(x1[j]);
    }
    *reinterpret_cast<short8*>(lx + wr_off) = xs;
  }
  __syncthreads();

  for (int ck = 0; ck < 8; ++ck) {
    const int curoff = (ck & 1) * 8192;
    const int nxtoff = ((ck & 1) ^ 1) * 8192;
    if (ck < 7) {
      x0 = *reinterpret_cast<const f32x4*>(xrow + (ck + 1) * 128);
      x1 = *reinterpret_cast<const f32x4*>(xrow + (ck + 1) * 128 + 4);
    }
#pragma unroll
    for (int ks = 0; ks < 4; ++ks) {
      const short8 a = *reinterpret_cast<const short8*>(
          lx + curoff + arow * 256 + ((ks * 64 + lq * 16) ^ ((arow & 7) << 4)));
#pragma unroll
      for (int i = 0; i < 3; ++i) {
        const short8 b = *reinterpret_cast<const short8*>(
            wbase + (long)i * 16384 + (ck * 4 + ks) * 512);
        acc[i] = __builtin_amdgcn_mfma_f32_16x16x32_bf16(a, b, acc[i], 0, 0, 0);
      }
    }
    __syncthreads();
    if (ck < 7) {
      short8 xs;
#pragma unroll
      for (int j = 0; j < 4; ++j) {
        xs[j] = (short)f32_to_bf16(x0[j]);
        xs[4 + j] = (short)f32_to_bf16(x1[j]);
      }
      *reinterpret_cast<short8*>(lx + nxtoff + wr_off) = xs;
      __syncthreads();
    }
  }

#pragma unroll
  for (int i = 0; i < 3; ++i) {
    const int nt = 3 * trio + i;
    const int mat = nt >> 2;
    const int dcol = ((nt & 3) << 4) | l16;
    const float bias = (mat == 0 ? bq : mat == 1 ? bk : bv)[dcol];
    const int c = dcol >> 5, lqp = (dcol >> 3) & 3, jj = dcol & 7;
#pragma unroll
    for (int rr = 0; rr < 4; ++rr) {
      const long t = rowbase + sub * 16 + lq * 4 + rr;
      const float sum = acc[i][rr] + bias;
      if (mat == 0) {
        Qf[(((t >> 4) * 2 + c) * 64 + lqp * 16 + (t & 15)) * 8 + jj] =
            f32_to_bf16(sum * 0.125f);  // fold 1/sqrt(64)
      } else if (mat == 1) {
        Kf[((((t >> 6) * 4 + ((t >> 4) & 3)) * 2 + c) * 64 + lqp * 16 +
            (t & 15)) * 8 + jj] = f32_to_bf16(sum);
      } else {
        Vf[((((t >> 6) * 4 + (dcol >> 4)) * 2 + ((t >> 5) & 1)) * 64 +
            ((t >> 3) & 3) * 16 + (dcol & 15)) * 8 + (t & 7)] =
            f32_to_bf16(sum);
      }
    }
  }
}

// ---------------- kernel 3: causal flash attention, 8-wave split-K ----------
// One 16-row Q tile per block; 8 waves split KV round-robin (kt = w, w+8,...);
// lane-local softmax via swapped MFMA operands; 8-way LDS combine.
__global__ __launch_bounds__(512) void attn_kernel(
    const unsigned short* __restrict__ Qf, const unsigned short* __restrict__ Kf,
    const unsigned short* __restrict__ Vf, float* __restrict__ out) {
  __shared__ __align__(16) unsigned short p_lds[8][16][72];  // [wave][q][k]
  __shared__ __align__(16) float lds_o[8][16][68];           // [wave][q][d]
  __shared__ float lds_ml[8][16][2];
  __shared__ float lds_gl[16];

  const int tid = threadIdx.x;
  const int lane = tid & 63;
  const int wave = tid >> 6;  // 0..7
  const int l16 = lane & 15, lq = lane >> 4;
  const int b = blockIdx.y;
  const int tile = 255 - blockIdx.x;  // heavy tiles dispatch first
  const int qbase = tile * 16;
  const long qrow = (long)b * SEQ + qbase;

  short8 qf[2];
#pragma unroll
  for (int c = 0; c < 2; ++c)
    qf[c] = *reinterpret_cast<const short8*>(
        Qf + ((qrow >> 4) * 2 + c) * 512 + lane * 8);

  f32x4 o[4];  // O^T: o[dt][r] = O[q=l16][d=dt*16+lq*4+r]
#pragma unroll
  for (int dt = 0; dt < 4; ++dt) o[dt] = (f32x4){0.f, 0.f, 0.f, 0.f};
  float m = -INFINITY, ell = 0.f;  // per-lane state for q = qbase + l16

  const long ktile0 = (long)b * 64;
  const int nkv = qbase / 64 + 1;  // KV tiles of 64 cols
  for (int kt = wave; kt < nkv; kt += 8) {
    const int kvbase = kt * 64;
    const unsigned short* kb = Kf + (ktile0 + kt) * 4096 + lane * 8;
    const unsigned short* vb = Vf + (ktile0 + kt) * 4096 + lane * 8;
    f32x4 s[4];  // S^T: s[ct][r] = S[q=l16][k=kvbase+ct*16+lq*4+r]
#pragma unroll
    for (int ct = 0; ct < 4; ++ct) s[ct] = (f32x4){0.f, 0.f, 0.f, 0.f};
#pragma unroll
    for (int ct = 0; ct < 4; ++ct)
#pragma unroll
      for (int c = 0; c < 2; ++c) {
        short8 kf = *reinterpret_cast<const short8*>(kb + (ct * 2 + c) * 512);
        s[ct] = __builtin_amdgcn_mfma_f32_16x16x32_bf16(kf, qf[c], s[ct], 0, 0, 0);
      }
    if (kt == nkv - 1) {  // only the diagonal tile needs masking
      const int qg = qbase + l16;
#pragma unroll
      for (int ct = 0; ct < 4; ++ct)
#pragma unroll
        for (int r = 0; r < 4; ++r)
          if (kvbase + ct * 16 + lq * 4 + r > qg) s[ct][r] = -INFINITY;
    }
    // lane-local softmax over 16 held k values + 4-lane-group reduce
    float mx = -INFINITY;
#pragma unroll
    for (int ct = 0; ct < 4; ++ct)
#pragma unroll
      for (int r = 0; r < 4; ++r) mx = fmaxf(mx, s[ct][r]);
    mx = fmaxf(mx, __shfl_xor(mx, 16, 64));
    mx = fmaxf(mx, __shfl_xor(mx, 32, 64));
    const float nm = fmaxf(m, mx);
    const float alpha = __expf(m - nm);  // exp(-inf)=0 on first tile
    float rs = 0.f;
#pragma unroll
    for (int ct = 0; ct < 4; ++ct)
#pragma unroll
      for (int r = 0; r < 4; ++r) {
        const float p = __expf(s[ct][r] - nm);
        s[ct][r] = p;
        rs += p;
      }
    rs += __shfl_xor(rs, 16, 64);
    rs += __shfl_xor(rs, 32, 64);
    ell = ell * alpha + rs;
    m = nm;
#pragma unroll
    for (int dt = 0; dt < 4; ++dt) o[dt] *= alpha;
    // P^T (regs) -> p_lds[q][k] -> B-frag for PV. Per-wave buffer, no barrier.
#pragma unroll
    for (int ct = 0; ct < 4; ++ct)
#pragma unroll
      for (int r = 0; r < 4; ++r)
        p_lds[wave][l16][ct * 16 + lq * 4 + r] = f32_to_bf16(s[ct][r]);
    short8 pf[2];
#pragma unroll
    for (int c = 0; c < 2; ++c)
      pf[c] = *reinterpret_cast<const short8*>(&p_lds[wave][l16][c * 32 + lq * 8]);
#pragma unroll
    for (int dt = 0; dt < 4; ++dt)
#pragma unroll
      for (int c = 0; c < 2; ++c) {
        short8 vf = *reinterpret_cast<const short8*>(vb + (dt * 2 + c) * 512);
        o[dt] = __builtin_amdgcn_mfma_f32_16x16x32_bf16(vf, pf[c], o[dt], 0, 0, 0);
      }
  }

  // ---- 8-way cross-wave combine ----
  if (lane < 16) {
    lds_ml[wave][l16][0] = m;
    lds_ml[wave][l16][1] = ell;
  }
  __syncthreads();
  float g = -INFINITY;
#pragma unroll
  for (int w2 = 0; w2 < 8; ++w2) g = fmaxf(g, lds_ml[w2][l16][0]);
  float gl = 0.f;
#pragma unroll
  for (int w2 = 0; w2 < 8; ++w2)
    gl += lds_ml[w2][l16][1] * __expf(lds_ml[w2][l16][0] - g);
  const float myscale = __expf(m - g);
  if (wave == 0 && lane < 16) lds_gl[l16] = gl;
#pragma unroll
  for (int dt = 0; dt < 4; ++dt)
#pragma unroll
    for (int r = 0; r < 4; ++r)
      lds_o[wave][l16][dt * 16 + lq * 4 + r] = o[dt][r] * myscale;
  __syncthreads();
#pragma unroll
  for (int j = 0; j < 2; ++j) {
    const int e = tid + 512 * j;
    const int row = e >> 6, col = e & 63;
    float sum = 0.f;
#pragma unroll
    for (int w2 = 0; w2 < 8; ++w2) sum += lds_o[w2][row][col];
    out[(qrow + row) * D_KV + col] = sum / lds_gl[row];
  }
}

// ---------------- launch ----------------------------------------------------
extern "C" void kernel_launch(void* const* d_in, const int* in_sizes, int n_in,
                              void* d_out, int out_size, void* d_ws, size_t ws_size,
                              hipStream_t stream) {
  const float* x  = (const float*)d_in[0];
  const float* wq = (const float*)d_in[1];
  const float* bq = (const float*)d_in[2];
  const float* wk = (const float*)d_in[3];
  const float* bk = (const float*)d_in[4];
  const float* wv = (const float*)d_in[5];
  const float* bv = (const float*)d_in[6];
  float* out = (float*)d_out;

  unsigned short* ws    = (unsigned short*)d_ws;
  unsigned short* wfrag = ws;               // 196608 shorts (384KB)
  unsigned short* Qf    = ws + 196608;      // 1048576 shorts
  unsigned short* Kf    = Qf + 1048576;
  unsigned short* Vf    = Kf + 1048576;

  wcvt_kernel<<<96, 256, 0, stream>>>(wq, wk, wv, wfrag);
  qkv_proj_kernel<<<512, 512, 0, stream>>>(x, wfrag, bq, bk, bv, Qf, Kf, Vf);
  dim3 ag(256, NBATCH);
  attn_kernel<<<ag, 512, 0, stream>>>(Qf, Kf, Vf, out);
}